// Round 11
// baseline (874.133 us; speedup 1.0000x reference)
//
#include <hip/hip_runtime.h>
#include <hip/hip_bf16.h>
#include <cstdint>
#include <cstddef>

#define EPSV 1e-5f

typedef float f32x4 __attribute__((ext_vector_type(4)));
typedef _Float16 f16x8 __attribute__((ext_vector_type(8)));
typedef unsigned short ushortx8 __attribute__((ext_vector_type(8)));

__device__ __forceinline__ unsigned short f2h(float f) {
  _Float16 h = (_Float16)f;
  return *reinterpret_cast<unsigned short*>(&h);
}

// LDS dest must be the WAVE-UNIFORM chunk base; HW adds lane*16.
__device__ __forceinline__ void gload16(const void* g, void* l) {
  __builtin_amdgcn_global_load_lds(
      (const __attribute__((address_space(1))) void*)g,
      (__attribute__((address_space(3))) void*)l, 16, 0, 0);
}

// ---------------- zero only the halo of xT [4,66,66,2048] ------------------
__global__ __launch_bounds__(256) void ocr_halo_zero(unsigned short* __restrict__ xT) {
  int e = blockIdx.x, b = blockIdx.y, t = threadIdx.x;
  ushortx8 z = {0, 0, 0, 0, 0, 0, 0, 0};
  if (e < 2) {
    int row = e ? 65 : 0;
    ushortx8* p = (ushortx8*)(xT + (size_t)(b * 66 + row) * 66 * 2048);
    for (int i = t; i < 66 * 256; i += 256) p[i] = z;
  } else {
    int col = (e == 3) ? 65 : 0;
    for (int idx = t; idx < 64 * 256; idx += 256) {
      int r = (idx >> 8) + 1, v = idx & 255;
      ((ushortx8*)(xT + ((size_t)(b * 66 + r) * 66 + col) * 2048))[v] = z;
    }
  }
}

// ------ x [4,2048,64,64] f32 -> xT [4,66,66,2048] f16 (padded, transposed) -
__global__ __launch_bounds__(256) void ocr_cvt_x(const float* __restrict__ x,
                                                 unsigned short* __restrict__ xT) {
  __shared__ float tile[64][65];
  int icb = blockIdx.x, h = blockIdx.y, b = blockIdx.z, t = threadIdx.x;
  const float* xp = x + ((size_t)b * 2048 + icb * 64) * 4096 + h * 64;
  #pragma unroll
  for (int r = 0; r < 16; ++r) {
    int icl = r * 4 + (t >> 6), w = t & 63;
    tile[icl][w] = xp[(size_t)icl * 4096 + w];
  }
  __syncthreads();
  #pragma unroll
  for (int it = 0; it < 2; ++it) {
    int w = it * 32 + (t >> 3), cb = (t & 7) * 8;
    ushortx8 o;
    #pragma unroll
    for (int j = 0; j < 8; ++j) o[j] = f2h(tile[cb + j][w]);
    *(ushortx8*)&xT[(((size_t)b * 66 + h + 1) * 66 + (w + 1)) * 2048 + icb * 64 + cb] = o;
  }
}

// ---------------- W_X [512,2048,3,3] f32 -> WT [9,512,2048] f16 ------------
__global__ __launch_bounds__(256) void ocr_cvt_w(const float* __restrict__ Wx,
                                                 unsigned short* __restrict__ WT) {
  int oc = blockIdx.x >> 3;
  int ic = (blockIdx.x & 7) * 256 + threadIdx.x;
  const float* wp = Wx + ((size_t)oc * 2048 + ic) * 9;
  float v[9];
  #pragma unroll
  for (int t = 0; t < 9; ++t) v[t] = wp[t];
  #pragma unroll
  for (int t = 0; t < 9; ++t)
    WT[((size_t)t * 512 + oc) * 2048 + ic] = f2h(v[t]);
}

// ---------------- fused f32 -> f16 for W_psi (131072) + W_g (524288) -------
__global__ __launch_bounds__(256) void ocr_cvt_h2(const float* __restrict__ inA,
                                                  unsigned short* __restrict__ outA,
                                                  const float* __restrict__ inB,
                                                  unsigned short* __restrict__ outB) {
  int i = blockIdx.x * 256 + threadIdx.x;
  if (i < 131072) outA[i] = f2h(inA[i]);
  if (i < 524288) outB[i] = f2h(inB[i]);
}

// ---------------- conv 3x3 2048->512, f16 MFMA, 12 waves, 128px/wave -------
// 768 thr / 12 waves: ws=wv&3 owns rows {2ws,2ws+1} (acc 4x8 = 64oc x 128px);
// tt=wv>>2 owns tap-third {3tt..3tt+2} -> dh=tt, dw=j. 36 LDS reads / 96 MFMA
// per wave-step (vs r9's 38/72): LDS ~5184 cyc == MFMA 5587 cyc, balanced.
// LDS: dbuf 2 x (A [tap9][kg4][65] 37888B-padded + B [row10][kg4][66] 43008B)
// = 161792B. r9-style single-syncthreads dbuf loop (issue-first, drain at
// barrier hidden under compute). 3-way tap reduction in two LDS phases.
__global__ __launch_bounds__(768, 3) void ocr_conv_mfma(const unsigned short* __restrict__ xT,
                                                        const unsigned short* __restrict__ WT,
                                                        float* __restrict__ Xf) {
  __shared__ __align__(16) char lds_raw[161792];
  float* red = (float*)lds_raw;

  const int t = threadIdx.x;
  const int wv = t >> 6, lane = t & 63;
  const int kg = lane >> 4, lc = lane & 15;
  const int ws = wv & 3, tt = wv >> 2;   // row-pair / tap-third (dh == tt)

  const int bx = blockIdx.x;
  const int hg  = bx & 7;                // XCD owns one h-band
  const int b   = (bx >> 3) & 3;
  const int oct = bx >> 5;
  const int oc0 = oct * 64, h0 = hg * 8;

  // staging: 79 chunks (0-36 A: 2340 cells /65, 37-78 B: 2640 cells /66);
  // wave w owns chunks w*7..w*7+6 (inactive past 78). Clamped dup loads for
  // pad/tail cells (never read). Wave-uniform LDS bases.
  const char* gp[7]; int lo[7]; bool go[7];
  #pragma unroll
  for (int i = 0; i < 7; ++i) {
    int c = wv * 7 + i;
    go[i] = c < 79;
    int cc = go[i] ? c : 0;
    if (cc < 37) {
      int cell = cc * 64 + lane; if (cell > 2339) cell = 2339;
      int r = cell / 65, col = cell - r * 65; if (col > 63) col = 63;
      int tap = r >> 2, kgs = r & 3;
      gp[i] = (const char*)WT + (size_t)(((tap * 512 + oc0 + col) * 2048) + kgs * 8) * 2;
      lo[i] = cc * 1024;
    } else {
      int c2 = cc - 37;
      int cell = c2 * 64 + lane; if (cell > 2639) cell = 2639;
      int r = cell / 66, col = cell - r * 66;
      int row = r >> 2, kgs = r & 3;
      gp[i] = (const char*)xT + (size_t)((((b * 66 + h0 + row) * 66 + col) * 2048) + kgs * 8) * 2;
      lo[i] = 37888 + c2 * 1024;
    }
  }

  f32x4 acc[4][8] = {};

  // prologue: stage step 0 into buffer 0
  #pragma unroll
  for (int i = 0; i < 7; ++i) if (go[i]) gload16(gp[i], lds_raw + lo[i]);
  __syncthreads();

  int cur = 0;
  #pragma unroll 1
  for (int step = 0; step < 64; ++step) {
    if (step < 63) {                      // issue next-step loads FIRST
      unsigned adv = (unsigned)(step + 1) * 64u;   // 32 ic = 64B per step
      int nxt = (cur ^ 1) * 80896;
      #pragma unroll
      for (int i = 0; i < 7; ++i) if (go[i]) gload16(gp[i] + adv, lds_raw + nxt + lo[i]);
    }
    const short* As = (const short*)(lds_raw + cur * 80896);
    const short* Bs = (const short*)(lds_raw + cur * 80896 + 37888);
    #pragma unroll
    for (int j = 0; j < 3; ++j) {
      const int tap = tt * 3 + j;         // dh = tt, dw = j
      f16x8 av[4];
      #pragma unroll
      for (int mi = 0; mi < 4; ++mi)
        av[mi] = *(const f16x8*)&As[((tap * 4 + kg) * 65 + mi * 16 + lc) * 8];
      #pragma unroll
      for (int hh = 0; hh < 2; ++hh) {
        const int row = 2 * ws + hh + tt;
        #pragma unroll
        for (int nw = 0; nw < 4; ++nw) {
          f16x8 bv = *(const f16x8*)&Bs[((row * 4 + kg) * 66 + nw * 16 + lc + j) * 8];
          #pragma unroll
          for (int mi = 0; mi < 4; ++mi)
            acc[mi][hh * 4 + nw] = __builtin_amdgcn_mfma_f32_16x16x32_f16(av[mi], bv, acc[mi][hh * 4 + nw], 0, 0, 0);
        }
      }
    }
    __syncthreads();   // drains staged loads (issued pre-compute: hidden)
    cur ^= 1;
  }

  // 3-way tap reduction through LDS (131KB region), then write
  if (tt == 2) {
    #pragma unroll
    for (int mi = 0; mi < 4; ++mi)
      #pragma unroll
      for (int ni = 0; ni < 8; ++ni)
        *(f32x4*)&red[((ws * 32 + mi * 8 + ni) * 64 + lane) * 4] = acc[mi][ni];
  }
  __syncthreads();
  if (tt == 1) {
    #pragma unroll
    for (int mi = 0; mi < 4; ++mi)
      #pragma unroll
      for (int ni = 0; ni < 8; ++ni) {
        f32x4 o = *(const f32x4*)&red[((ws * 32 + mi * 8 + ni) * 64 + lane) * 4];
        *(f32x4*)&red[((ws * 32 + mi * 8 + ni) * 64 + lane) * 4] = acc[mi][ni] + o;
      }
  }
  __syncthreads();
  if (tt == 0) {
    #pragma unroll
    for (int mi = 0; mi < 4; ++mi) {
      #pragma unroll
      for (int ni = 0; ni < 8; ++ni) {
        f32x4 o = *(const f32x4*)&red[((ws * 32 + mi * 8 + ni) * 64 + lane) * 4];
        f32x4 s = acc[mi][ni] + o;
        int hh = ni >> 2, nw = ni & 3;
        int h = h0 + 2 * ws + hh;
        #pragma unroll
        for (int r = 0; r < 4; ++r) {
          int oc = oc0 + mi * 16 + (lane >> 4) * 4 + r;
          int w = nw * 16 + lc;
          Xf[(((size_t)b * 512 + oc) * 64 + h) * 64 + w] = s[r];
        }
      }
    }
  }
}

// ------ f16 MFMA GEMM (counted-vmcnt dbuf): C[b,O,4096]=A[O,K]@B[b,4096,LDB]
template<int K, int OT, int NT, int NWM, int NWN, int LDB>
__global__ __launch_bounds__(256) void ocr_gemm_h(const unsigned short* __restrict__ Ah,
                                                  const unsigned short* __restrict__ Bh,
                                                  float* __restrict__ Cm, int O) {
  static_assert(NT == 128, "NT fixed");
  constexpr int MI = OT / NWM / 16;
  constexpr int NI = NT / NWN / 16;
  constexpr int SA = OT + 2, SB = NT + 2;
  constexpr int ACELL = 4 * OT / 256;
  constexpr int ABUF = 4 * SA * 8;   // shorts per buffer
  constexpr int BBUF = 4 * SB * 8;
  constexpr int NS = K / 32;
  constexpr int LPW = ACELL + 2;     // loads per wave per step
  __shared__ __align__(16) short As_s[2 * ABUF];
  __shared__ __align__(16) short Bs_s[2 * BBUF];

  const int t = threadIdx.x;
  const int wv = t >> 6, lane = t & 63;
  const int kg = lane >> 4, lc = lane & 15;
  const int wm = wv / NWN, wn = wv % NWN;

  const int n0 = blockIdx.x * NT, o0 = blockIdx.y * OT, b = blockIdx.z;

  const char* aBase[ACELL]; int aLds[ACELL];
  #pragma unroll
  for (int r = 0; r < ACELL; ++r) {
    int flat0 = r * 256 + (t & 448);               // wave base
    int flat  = flat0 + lane;
    int kgs = flat / OT, ol = flat % OT;
    aBase[r] = (const char*)(Ah + ((size_t)(o0 + ol)) * K + kgs * 8);
    aLds[r] = ((flat0 / OT) * SA + (flat0 % OT)) * 16;  // bytes, wave-uniform
  }
  const char* bBase[2]; int bLds[2];
  #pragma unroll
  for (int r = 0; r < 2; ++r) {
    int flat0 = r * 256 + (t & 448);
    int flat  = flat0 + lane;
    int kgs = flat >> 7, nl = flat & 127;
    bBase[r] = (const char*)(Bh + ((size_t)b * 4096 + n0 + nl) * LDB + kgs * 8);
    bLds[r] = ((flat0 >> 7) * SB + (flat0 & 127)) * 16;
  }

  f32x4 acc[MI][NI] = {};
  #pragma unroll
  for (int r = 0; r < ACELL; ++r) gload16(aBase[r], (char*)As_s + aLds[r]);
  #pragma unroll
  for (int r = 0; r < 2; ++r) gload16(bBase[r], (char*)Bs_s + bLds[r]);
  asm volatile("s_waitcnt vmcnt(0)" ::: "memory");
  __builtin_amdgcn_s_barrier();

  int cur = 0;
  #pragma unroll 1
  for (int step = 0; step < NS; ++step) {
    if (step + 1 < NS) {
      unsigned adv = (unsigned)(step + 1) * 64u;
      int nA = (cur ^ 1) * ABUF * 2, nB = (cur ^ 1) * BBUF * 2;  // bytes
      #pragma unroll
      for (int r = 0; r < ACELL; ++r) gload16(aBase[r] + adv, (char*)As_s + nA + aLds[r]);
      #pragma unroll
      for (int r = 0; r < 2; ++r) gload16(bBase[r] + adv, (char*)Bs_s + nB + bLds[r]);
      if constexpr (LPW == 3) asm volatile("s_waitcnt vmcnt(3)" ::: "memory");
      else                    asm volatile("s_waitcnt vmcnt(4)" ::: "memory");
    } else {
      asm volatile("s_waitcnt vmcnt(0)" ::: "memory");
    }
    __builtin_amdgcn_s_barrier();

    const short* As = As_s + cur * ABUF;
    const short* Bsc = Bs_s + cur * BBUF;
    f16x8 av[MI], bv[NI];
    #pragma unroll
    for (int mi = 0; mi < MI; ++mi)
      av[mi] = *(const f16x8*)&As[(kg * SA + wm * (MI * 16) + mi * 16 + lc) * 8];
    #pragma unroll
    for (int ni = 0; ni < NI; ++ni)
      bv[ni] = *(const f16x8*)&Bsc[(kg * SB + wn * (NI * 16) + ni * 16 + lc) * 8];
    __builtin_amdgcn_s_setprio(1);
    #pragma unroll
    for (int mi = 0; mi < MI; ++mi)
      #pragma unroll
      for (int ni = 0; ni < NI; ++ni)
        acc[mi][ni] = __builtin_amdgcn_mfma_f32_16x16x32_f16(av[mi], bv[ni], acc[mi][ni], 0, 0, 0);
    __builtin_amdgcn_s_setprio(0);
    asm volatile("s_waitcnt lgkmcnt(0)" ::: "memory");
    __builtin_amdgcn_sched_barrier(0);
    __builtin_amdgcn_s_barrier();
    cur ^= 1;
  }
  #pragma unroll
  for (int mi = 0; mi < MI; ++mi) {
    #pragma unroll
    for (int ni = 0; ni < NI; ++ni) {
      int n = n0 + wn * (NI * 16) + ni * 16 + lc;
      #pragma unroll
      for (int r = 0; r < 4; ++r) {
        int oc = o0 + wm * (MI * 16) + mi * 16 + (lane >> 4) * 4 + r;
        Cm[((size_t)b * O + oc) * 4096 + n] = acc[mi][ni][r];
      }
    }
  }
}

// ------- transpose-convert + fused BN/relu: f32 [b,C,4096] -> f16 ----------
__global__ __launch_bounds__(256) void ocr_t2h(const float* __restrict__ in,
                                               const float* __restrict__ scale,
                                               const float* __restrict__ shift,
                                               unsigned short* __restrict__ out,
                                               int C, int coff) {
  __shared__ float tile[64][65];
  int n0 = blockIdx.x * 64, c0 = blockIdx.y * 64, b = blockIdx.z;
  int t = threadIdx.x;
  #pragma unroll
  for (int r = 0; r < 16; ++r) {
    int c_l = r * 4 + (t >> 6), n_l = t & 63;
    tile[c_l][n_l] = in[((size_t)(b * C + c0 + c_l)) * 4096 + n0 + n_l];
  }
  __syncthreads();
  int n_l = t >> 2, cb = (t & 3) * 16;
  ushortx8 o0v, o1v;
  #pragma unroll
  for (int j = 0; j < 8; ++j) {
    int c = c0 + cb + j;
    o0v[j] = f2h(fmaxf(0.f, tile[cb + j][n_l] * scale[c] + shift[c]));
  }
  #pragma unroll
  for (int j = 0; j < 8; ++j) {
    int c = c0 + cb + 8 + j;
    o1v[j] = f2h(fmaxf(0.f, tile[cb + 8 + j][n_l] * scale[c] + shift[c]));
  }
  size_t base = ((size_t)b * 4096 + n0 + n_l) * 1024 + coff + c0 + cb;
  *(ushortx8*)&out[base] = o0v;
  *(ushortx8*)&out[base + 8] = o1v;
}

// ---------------- per-channel stats over [4][C][4096] -> scale/shift -------
__global__ __launch_bounds__(256) void ocr_chan_stats(const float* __restrict__ buf,
                                                      const float* __restrict__ gamma,
                                                      const float* __restrict__ beta,
                                                      float* __restrict__ scale,
                                                      float* __restrict__ shift, int C) {
  int c = blockIdx.x, t = threadIdx.x;
  float s = 0.f, q = 0.f;
  for (int b = 0; b < 4; ++b) {
    const float* p = buf + ((size_t)b * C + c) * 4096;
    for (int i = t; i < 4096; i += 256) { float v = p[i]; s += v; q += v * v; }
  }
  __shared__ float ls[256], lq[256];
  ls[t] = s; lq[t] = q; __syncthreads();
  for (int off = 128; off > 0; off >>= 1) {
    if (t < off) { ls[t] += ls[t + off]; lq[t] += lq[t + off]; }
    __syncthreads();
  }
  if (t == 0) {
    float mean = ls[0] / 16384.f;
    float var  = lq[0] / 16384.f - mean * mean;
    float sc   = gamma[c] * rsqrtf(var + EPSV);
    scale[c] = sc; shift[c] = beta[c] - mean * sc;
  }
}

// ---------------- L = W_L @ llf + b_L  (4-deep MLP on c) -------------------
__global__ __launch_bounds__(256) void ocr_lproj(const float* __restrict__ llf,
                                                 const float* __restrict__ WL,
                                                 const float* __restrict__ bL,
                                                 float* __restrict__ L) {
  int h = blockIdx.x, b = blockIdx.y;
  int t = threadIdx.x, w = t & 63, csub = t >> 6;
  float acc[19];
  #pragma unroll
  for (int k = 0; k < 19; ++k) acc[k] = 0.f;
  const float* base = llf + ((size_t)b * 1024 + csub * 256) * 4096 + h * 64 + w;
  #pragma unroll 1
  for (int c4 = 0; c4 < 64; ++c4) {
    float lv[4];
    #pragma unroll
    for (int i = 0; i < 4; ++i) lv[i] = base[(size_t)(c4 + i * 64) * 4096];
    #pragma unroll
    for (int i = 0; i < 4; ++i) {
      const float* wl = &WL[csub * 256 + c4 + i * 64];
      #pragma unroll
      for (int k = 0; k < 19; ++k) acc[k] += wl[k * 1024] * lv[i];
    }
  }
  __shared__ float red[4][64][19];
  #pragma unroll
  for (int k = 0; k < 19; ++k) red[csub][w][k] = acc[k];
  __syncthreads();
  if (csub == 0) {
    #pragma unroll
    for (int k = 0; k < 19; ++k) {
      float s = red[0][w][k] + red[1][w][k] + red[2][w][k] + red[3][w][k] + bL[k];
      L[((size_t)b * 19 + k) * 4096 + h * 64 + w] = s;
    }
  }
}

// ---------------- in-place softmax over last dim (4096) --------------------
__global__ __launch_bounds__(256) void ocr_softmax4096(float* __restrict__ buf) {
  int row = blockIdx.x, t = threadIdx.x;
  float* p = buf + (size_t)row * 4096;
  __shared__ float ls[256];
  float m = -1e30f;
  for (int i = t; i < 4096; i += 256) m = fmaxf(m, p[i]);
  ls[t] = m; __syncthreads();
  for (int off = 128; off > 0; off >>= 1) { if (t < off) ls[t] = fmaxf(ls[t], ls[t + off]); __syncthreads(); }
  m = ls[0]; __syncthreads();
  float s = 0.f;
  for (int i = t; i < 4096; i += 256) { float e = __expf(p[i] - m); p[i] = e; s += e; }
  ls[t] = s; __syncthreads();
  for (int off = 128; off > 0; off >>= 1) { if (t < off) ls[t] += ls[t + off]; __syncthreads(); }
  float inv = 1.f / ls[0];
  for (int i = t; i < 4096; i += 256) p[i] *= inv;
}

// -------- f_k[b,c,k] = sum_n M[b,k,n] * relu(Xf*sc+sh)[b,c,n] (fused BN) ---
__global__ __launch_bounds__(256) void ocr_fk(const float* __restrict__ M,
                                              const float* __restrict__ Xf,
                                              const float* __restrict__ scale,
                                              const float* __restrict__ shift,
                                              float* __restrict__ fk) {
  int c = blockIdx.x, b = blockIdx.y, t = threadIdx.x;
  float acc[19];
  #pragma unroll
  for (int k = 0; k < 19; ++k) acc[k] = 0.f;
  const float* xp = Xf + ((size_t)b * 512 + c) * 4096;
  const float* mp = M + (size_t)b * 19 * 4096;
  float sc = scale[c], sh = shift[c];
  for (int n = t; n < 4096; n += 256) {
    float xv = fmaxf(0.f, xp[n] * sc + sh);
    #pragma unroll
    for (int k = 0; k < 19; ++k) acc[k] += mp[k * 4096 + n] * xv;
  }
  __shared__ float red[19 * 256];
  #pragma unroll
  for (int k = 0; k < 19; ++k) red[k * 256 + t] = acc[k];
  __syncthreads();
  for (int off = 128; off > 0; off >>= 1) {
    if (t < off) {
      #pragma unroll
      for (int k = 0; k < 19; ++k) red[k * 256 + t] += red[k * 256 + t + off];
    }
    __syncthreads();
  }
  if (t < 19) fk[((size_t)b * 512 + c) * 19 + t] = red[t * 256];
}

// ---------------- q/d fused: qry + dlt in one launch -----------------------
__global__ __launch_bounds__(256) void ocr_qd2(const float* __restrict__ Wphi,
                                               const float* __restrict__ Wdelta,
                                               const float* __restrict__ fk,
                                               float* __restrict__ qry,
                                               float* __restrict__ dlt) {
  int blk = blockIdx.x;
  const float* Wm = (blk < 76) ? Wphi : Wdelta;
  float* out = (blk < 76) ? qry : dlt;
  int tid = (blk < 76 ? blk : blk - 76) * 256 + threadIdx.x;
  if (tid >= 4 * 256 * 19) return;
  int k = tid % 19, o = (tid / 19) % 256, b = tid / (19 * 256);
  const float* fp = fk + (size_t)b * 512 * 19 + k;
  const float* wp = Wm + (size_t)o * 512;
  float acc = 0.f;
  for (int c = 0; c < 512; ++c) acc += wp[c] * fp[c * 19];
  out[tid] = acc;
}

// ---------------- BN76 fused: qry (blocks 0-255) + dlt (256-511) -----------
__global__ __launch_bounds__(128) void ocr_bn76x2(float* __restrict__ qry,
                                                  float* __restrict__ dlt,
                                                  const float* __restrict__ g_phi,
                                                  const float* __restrict__ be_phi,
                                                  const float* __restrict__ g_delta,
                                                  const float* __restrict__ be_delta) {
  bool second = blockIdx.x >= 256;
  int o = blockIdx.x & 255, t = threadIdx.x;
  float* buf = second ? dlt : qry;
  const float* gamma = second ? g_delta : g_phi;
  const float* beta  = second ? be_delta : be_phi;
  bool act = t < 76;
  float v = 0.f;
  size_t idx = 0;
  if (act) {
    int b = t / 19, k = t % 19;
    idx = ((size_t)b * 256 + o) * 19 + k;
    v = buf[idx];
  }
  __shared__ float ls[128], lq[128];
  ls[t] = act ? v : 0.f; lq[t] = act ? v * v : 0.f; __syncthreads();
  for (int off = 64; off > 0; off >>= 1) { if (t < off) { ls[t] += ls[t + off]; lq[t] += lq[t + off]; } __syncthreads(); }
  __shared__ float s_sc, s_sh;
  if (t == 0) {
    float mean = ls[0] / 76.f;
    float var  = lq[0] / 76.f - mean * mean;
    float sc   = gamma[o] * rsqrtf(var + EPSV);
    s_sc = sc; s_sh = beta[o] - mean * sc;
  }
  __syncthreads();
  if (act) buf[idx] = fmaxf(0.f, v * s_sc + s_sh);
}

// ------- logit + softmax over nc(19), key BN fused, 4-deep MLP -------------
__global__ __launch_bounds__(256) void ocr_attn(const float* __restrict__ query,
                                                const float* __restrict__ key,
                                                const float* __restrict__ scale,
                                                const float* __restrict__ shift,
                                                float* __restrict__ attn) {
  int n0 = blockIdx.x * 64, b = blockIdx.y;
  int t = threadIdx.x, nl = t & 63, qsub = t >> 6;
  __shared__ float ql[256 * 19];
  for (int i = t; i < 256 * 19; i += 256) ql[i] = query[(size_t)b * 256 * 19 + i];
  __syncthreads();
  float acc[19];
  #pragma unroll
  for (int k = 0; k < 19; ++k) acc[k] = 0.f;
  const float* kp = key + ((size_t)b * 256 + qsub * 64) * 4096 + n0 + nl;
  #pragma unroll 1
  for (int q4 = 0; q4 < 64; q4 += 4) {
    float kv[4];
    #pragma unroll
    for (int i = 0; i < 4; ++i) kv[i] = kp[(size_t)(q4 + i) * 4096];
    #pragma unroll
    for (int i = 0; i < 4; ++i) {
      int ch = qsub * 64 + q4 + i;
      float kva = fmaxf(0.f, kv[i] * scale[ch] + shift[ch]);
      const float* qq = &ql[ch * 19];
      #pragma unroll
      for (int k = 0; k < 19; ++k) acc[k] += qq[k] * kva;
    }
  }
  __shared__ float red[4][64][19];
  #pragma unroll
  for (int k = 0; k < 19; ++k) red[qsub][nl][k] = acc[k];
  __syncthreads();
  if (qsub == 0) {
    float v[19]; float m = -1e30f;
    #pragma unroll
    for (int k = 0; k < 19; ++k) {
      v[k] = red[0][nl][k] + red[1][nl][k] + red[2][nl][k] + red[3][nl][k];
      m = fmaxf(m, v[k]);
    }
    float s = 0.f;
    #pragma unroll
    for (int k = 0; k < 19; ++k) { v[k] = __expf(v[k] - m); s += v[k]; }
    float inv = 1.f / s;
    #pragma unroll
    for (int k = 0; k < 19; ++k)
      attn[((size_t)b * 19 + k) * 4096 + n0 + nl] = v[k] * inv;
  }
}

// ---------------- Wd[b,o,k] = sum_q W_rho[o,q] * dlt[b,q,k] ----------------
__global__ __launch_bounds__(256) void ocr_wd(const float* __restrict__ Wrho,
                                              const float* __restrict__ dlt,
                                              float* __restrict__ Wd) {
  int tid = blockIdx.x * 256 + threadIdx.x;
  if (tid >= 4 * 512 * 19) return;
  int k = tid % 19, o = (tid / 19) % 512, b = tid / (19 * 512);
  const float* dp = dlt + (size_t)b * 256 * 19 + k;
  const float* wp = Wrho + (size_t)o * 256;
  float acc = 0.f;
  for (int q = 0; q < 256; ++q) acc += wp[q] * dp[q * 19];
  Wd[tid] = acc;
}

// ------- Gram partials: G[b] += attn_chunk @ attn_chunk^T, RS[b] += rowsum -
__global__ __launch_bounds__(384) void ocr_gram(const float* __restrict__ attn,
                                                float* __restrict__ G,
                                                float* __restrict__ RS) {
  __shared__ float al[19][513];
  int n0 = blockIdx.x * 512, b = blockIdx.y, t = threadIdx.x;
  for (int i = t; i < 19 * 512; i += 384) {
    int k = i >> 9, n = i & 511;
    al[k][n] = attn[((size_t)b * 19 + k) * 4096 + n0 + n];
  }
  __syncthreads();
  if (t < 361) {
    int k1 = t / 19, k2 = t % 19;
    float s = 0.f;
    for (int n = 0; n < 512; ++n) s += al[k1][n] * al[k2][n];
    atomicAdd(&G[(b * 19 + k1) * 19 + k2], s);
  } else if (t < 380) {
    int k = t - 361;
    float s = 0.f;
    for (int n = 0; n < 512; ++n) s += al[k][n];
    atomicAdd(&RS[b * 19 + k], s);
  }
}

// ------- Xobj scale/shift from Gram: one block of 512 (one thread per o) ---
__global__ __launch_bounds__(512) void ocr_xobj_fin(const float* __restrict__ Wd,
                                                    const float* __restrict__ G,
                                                    const float* __restrict__ RS,
                                                    const float* __restrict__ gamma,
                                                    const float* __restrict__ beta,
                                                    float* __restrict__ scale,
                                                    float* __restrict__ shift) {
  int o = threadIdx.x;
  float s = 0.f, q = 0.f;
  for (int b = 0; b < 4; ++b) {
    float wd[19];
    #pragma unroll
    for (int k = 0; k < 19; ++k) wd[k] = Wd[((size_t)b * 512 + o) * 19 + k];
    const float* g = &G[b * 361];
    const float* rs = &RS[b * 19];
    #pragma unroll
    for (int k = 0; k < 19; ++k) s += wd[k] * rs[k];
    for (int k1 = 0; k1 < 19; ++k1) {
      float tacc = 0.f;
      #pragma unroll
      for (int k2 = 0; k2 < 19; ++k2) tacc += g[k1 * 19 + k2] * wd[k2];
      q += wd[k1] * tacc;
    }
  }
  float mean = s / 16384.f;
  float var  = q / 16384.f - mean * mean;
  float sc   = gamma[o] * rsqrtf(var + EPSV);
  scale[o] = sc; shift[o] = beta[o] - mean * sc;
}

// ---------------- Xobj apply: relu(scale*(Wd@attn)+shift) -> concat f16 ----
__global__ __launch_bounds__(512) void ocr_xobj_apply(const float* __restrict__ Wd,
                                                      const float* __restrict__ attn,
                                                      const float* __restrict__ scale,
                                                      const float* __restrict__ shift,
                                                      unsigned short* __restrict__ ch) {
  __shared__ float al[19][256];
  int n0 = blockIdx.x * 256, b = blockIdx.y, o = threadIdx.x;
  for (int idx = o; idx < 19 * 256; idx += 512) {
    int k = idx >> 8, nl = idx & 255;
    al[k][nl] = attn[((size_t)b * 19 + k) * 4096 + n0 + nl];
  }
  float wd[19];
  #pragma unroll
  for (int k = 0; k < 19; ++k) wd[k] = Wd[((size_t)b * 512 + o) * 19 + k];
  float sc = scale[o], sh = shift[o];
  __syncthreads();
  #pragma unroll 1
  for (int nl = 0; nl < 256; ++nl) {
    float v = 0.f;
    #pragma unroll
    for (int k = 0; k < 19; ++k) v += wd[k] * al[k][nl];
    v = fmaxf(0.f, v * sc + sh);
    ch[((size_t)b * 4096 + n0 + nl) * 1024 + 512 + o] = f2h(v);
  }
}

// ---- out[b,19,n] = W_out @ relu(Xbar*sc+sh) + b_out (BN fused, 4-MLP) -----
__global__ __launch_bounds__(256) void ocr_out(const float* __restrict__ Wout,
                                               const float* __restrict__ bout,
                                               const float* __restrict__ Xbar,
                                               const float* __restrict__ scale,
                                               const float* __restrict__ shift,
                                               float* __restrict__ out) {
  int n0 = blockIdx.x * 64, b = blockIdx.y;
  int t = threadIdx.x, nl = t & 63, csub = t >> 6;
  float acc[19];
  #pragma unroll
  for (int k = 0; k < 19; ++k) acc[k] = 0.f;
  const float* base = Xbar + ((size_t)b * 512 + csub * 128) * 4096 + n0 + nl;
  #pragma unroll 1
  for (int c4 = 0; c4 < 128; c4 += 4) {
    float xv[4];
    #pragma unroll
    for (int i = 0; i < 4; ++i) xv[i] = base[(size_t)(c4 + i) * 4096];
    #pragma unroll
    for (int i = 0; i < 4; ++i) {
      int chn = csub * 128 + c4 + i;
      float a = fmaxf(0.f, xv[i] * scale[chn] + shift[chn]);
      #pragma unroll
      for (int k = 0; k < 19; ++k) acc[k] += Wout[k * 512 + chn] * a;
    }
  }
  __shared__ float red[4][64][19];
  #pragma unroll
  for (int k = 0; k < 19; ++k) red[csub][nl][k] = acc[k];
  __syncthreads();
  if (csub == 0) {
    #pragma unroll
    for (int k = 0; k < 19; ++k) {
      float s = red[0][nl][k] + red[1][nl][k] + red[2][nl][k] + red[3][nl][k] + bout[k];
      out[((size_t)b * 19 + k) * 4096 + n0 + nl] = s;
    }
  }
}

// ---------------------------------------------------------------------------
extern "C" void kernel_launch(void* const* d_in, const int* in_sizes, int n_in,
                              void* d_out, int out_size, void* d_ws, size_t ws_size,
                              hipStream_t stream) {
  const float* x    = (const float*)d_in[0];
  const float* llf  = (const float*)d_in[1];
  const float* W_L  = (const float*)d_in[2];
  const float* b_L  = (const float*)d_in[3];
  const float* W_X  = (const float*)d_in[4];
  const float* g_X  = (const float*)d_in[5];
  const float* be_X = (const float*)d_in[6];
  const float* W_phi = (const float*)d_in[7];
  const float* g_phi = (const float*)d_in[8];
  const float* be_phi = (const float*)d_in[9];
  const float* W_psi = (const float*)d_in[10];
  const float* g_psi = (const float*)d_in[11];
  const float* be_psi = (const float*)d_in[12];
  const float* W_delta = (const float*)d_in[13];
  const float* g_delta = (const float*)d_in[14];
  const float* be_delta = (const float*)d_in[15];
  const float* W_rho = (const float*)d_in[16];
  const float* g_rho = (const float*)d_in[17];
  const float* be_rho = (const float*)d_in[18];
  const float* W_g  = (const float*)d_in[19];
  const float* g_g  = (const float*)d_in[20];
  const float* be_g = (const float*)d_in[21];
  const float* W_out = (const float*)d_in[22];
  const float* b_out = (const float*)d_in[23];

  float* ws = (float*)d_ws;
  float* Xf = ws;                                        // 8388608 fl, persistent (raw conv out)
  float* U  = ws + 8388608;
  // conv-stage aliases (dead after conv):
  unsigned short* xT = (unsigned short*)U;               // 35684352 u16 = 17842176 fl
  unsigned short* WT = (unsigned short*)(U + 17842176);  // 9437184 u16 (ends 22560768 fl)
  // post-conv buffers (overlap xT/WT region):
  unsigned short* concat_h = (unsigned short*)U;         // [b][4096][1024] f16 = 8388608 fl
  float* key  = U + 8388608;                             // 4194304 fl (raw)
  float* Xbar = U + 12582912;                            // 8388608 fl (raw, ends 20971520)
  // small region beyond WT end (never overlaps conv data):
  float* SM   = U + 22560768;
  float* M     = SM;                                     // 311296
  float* attnb = SM + 311296;                            // 311296
  float* fk    = SM + 622592;                            // 38912
  float* qry   = SM + 661504;                            // 19456
  float* dlt   = SM + 680960;                            // 19456
  float* Wd    = SM + 700416;                            // 38912
  float* st    = SM + 739328;                            // 4096
  unsigned short* Wpsi_h = (unsigned short*)(SM + 743424);  // 131072 u16
  unsigned short* Wg_h   = (unsigned short*)(SM + 808960);  // 524288 u16
  float* Gm    = SM + 1071104;                           // 4*361 = 1444
  float* RSm   = SM + 1072548;                           // 4*19  = 76
  float* scX = st,        *shX = st + 512;
  float* scP = st + 1024, *shP = st + 1280;
  float* scR = st + 1536, *shR = st + 2048;
  float* scG = st + 2560, *shG = st + 3072;

  // 0. prep: halo-zero (border cells only) + f16 conversions
  ocr_halo_zero<<<dim3(4, 4), 256, 0, stream>>>(xT);
  ocr_cvt_x<<<dim3(32, 64, 4), 256, 0, stream>>>(x, xT);
  ocr_cvt_w<<<dim3(4096), 256, 0, stream>>>(W_X, WT);
  ocr_cvt_h2<<<dim3(2048), 256, 0, stream>>>(W_psi, Wpsi_h, W_g, Wg_h);
  hipMemsetAsync(Gm, 0, 1520 * sizeof(float), stream);

  // 1. conv (f16 MFMA, 12 waves, 128px/wave, single-barrier dbuf) -> Xf raw
  ocr_conv_mfma<<<dim3(256), 768, 0, stream>>>(xT, WT, Xf);

  // 2. BN(X) stats only; apply is fused into t2h and fk
  ocr_chan_stats<<<dim3(512), 256, 0, stream>>>(Xf, g_X, be_X, scX, shX, 512);
  // 3. Xf -> concat_h cols [0,512) f16 transposed (BN+relu fused)
  ocr_t2h<<<dim3(64, 8, 4), 256, 0, stream>>>(Xf, scX, shX, concat_h, 512, 0);
  // 4. region head: L -> softmax -> f_k (BN fused) -> query/delta + BN76
  ocr_lproj<<<dim3(64, 4), 256, 0, stream>>>(llf, W_L, b_L, M);
  ocr_softmax4096<<<dim3(76), 256, 0, stream>>>(M);
  ocr_fk<<<dim3(512, 4), 256, 0, stream>>>(M, Xf, scX, shX, fk);
  ocr_qd2<<<dim3(152), 256, 0, stream>>>(W_phi, W_delta, fk, qry, dlt);
  ocr_bn76x2<<<dim3(512), 128, 0, stream>>>(qry, dlt, g_phi, be_phi, g_delta, be_delta);
  // 5. key_raw = W_psi @ concat (f16 MFMA); BN stats; apply fused into attn
  ocr_gemm_h<512, 64, 128, 2, 2, 1024><<<dim3(32, 4, 4), 256, 0, stream>>>(Wpsi_h, concat_h, key, 256);
  ocr_chan_stats<<<dim3(256), 256, 0, stream>>>(key, g_psi, be_psi, scP, shP, 256);
  // 6. attention softmax over nc (key BN+relu fused)
  ocr_attn<<<dim3(64, 4), 256, 0, stream>>>(qry, key, scP, shP, attnb);
  // 7. X_obj = BN(relu(W_rho @ delta @ attn)); stats via Gram algebra (K=19)
  ocr_wd<<<dim3(152), 256, 0, stream>>>(W_rho, dlt, Wd);
  ocr_gram<<<dim3(8, 4), 384, 0, stream>>>(attnb, Gm, RSm);
  ocr_xobj_fin<<<dim3(1), 512, 0, stream>>>(Wd, Gm, RSm, g_rho, be_rho, scR, shR);
  ocr_xobj_apply<<<dim3(16, 4), 512, 0, stream>>>(Wd, attnb, scR, shR, concat_h);
  // 8. Xbar_raw = W_g @ concat (f16 MFMA, K=1024); BN stats; apply fused in out
  ocr_gemm_h<1024, 128, 128, 2, 2, 1024><<<dim3(32, 4, 4), 256, 0, stream>>>(Wg_h, concat_h, Xbar, 512);
  ocr_chan_stats<<<dim3(512), 256, 0, stream>>>(Xbar, g_g, be_g, scG, shG, 512);
  // 9. output projection (Xbar BN+relu fused, 4-deep MLP)
  ocr_out<<<dim3(64, 4), 256, 0, stream>>>(W_out, b_out, Xbar, scG, shG, (float*)d_out);
}

// Round 12
// 736.724 us; speedup vs baseline: 1.1865x; 1.1865x over previous
//
#include <hip/hip_runtime.h>
#include <hip/hip_bf16.h>
#include <cstdint>
#include <cstddef>

#define EPSV 1e-5f

typedef float f32x4 __attribute__((ext_vector_type(4)));
typedef _Float16 f16x8 __attribute__((ext_vector_type(8)));
typedef unsigned short ushortx8 __attribute__((ext_vector_type(8)));

__device__ __forceinline__ unsigned short f2h(float f) {
  _Float16 h = (_Float16)f;
  return *reinterpret_cast<unsigned short*>(&h);
}

// LDS dest must be the WAVE-UNIFORM chunk base; HW adds lane*16.
__device__ __forceinline__ void gload16(const void* g, void* l) {
  __builtin_amdgcn_global_load_lds(
      (const __attribute__((address_space(1))) void*)g,
      (__attribute__((address_space(3))) void*)l, 16, 0, 0);
}

// ---------------- zero only the halo of xT [4,66,66,2048] ------------------
__global__ __launch_bounds__(256) void ocr_halo_zero(unsigned short* __restrict__ xT) {
  int e = blockIdx.x, b = blockIdx.y, t = threadIdx.x;
  ushortx8 z = {0, 0, 0, 0, 0, 0, 0, 0};
  if (e < 2) {
    int row = e ? 65 : 0;
    ushortx8* p = (ushortx8*)(xT + (size_t)(b * 66 + row) * 66 * 2048);
    for (int i = t; i < 66 * 256; i += 256) p[i] = z;
  } else {
    int col = (e == 3) ? 65 : 0;
    for (int idx = t; idx < 64 * 256; idx += 256) {
      int r = (idx >> 8) + 1, v = idx & 255;
      ((ushortx8*)(xT + ((size_t)(b * 66 + r) * 66 + col) * 2048))[v] = z;
    }
  }
}

// ------ x [4,2048,64,64] f32 -> xT [4,66,66,2048] f16 (padded, transposed) -
__global__ __launch_bounds__(256) void ocr_cvt_x(const float* __restrict__ x,
                                                 unsigned short* __restrict__ xT) {
  __shared__ float tile[64][65];
  int icb = blockIdx.x, h = blockIdx.y, b = blockIdx.z, t = threadIdx.x;
  const float* xp = x + ((size_t)b * 2048 + icb * 64) * 4096 + h * 64;
  #pragma unroll
  for (int r = 0; r < 16; ++r) {
    int icl = r * 4 + (t >> 6), w = t & 63;
    tile[icl][w] = xp[(size_t)icl * 4096 + w];
  }
  __syncthreads();
  #pragma unroll
  for (int it = 0; it < 2; ++it) {
    int w = it * 32 + (t >> 3), cb = (t & 7) * 8;
    ushortx8 o;
    #pragma unroll
    for (int j = 0; j < 8; ++j) o[j] = f2h(tile[cb + j][w]);
    *(ushortx8*)&xT[(((size_t)b * 66 + h + 1) * 66 + (w + 1)) * 2048 + icb * 64 + cb] = o;
  }
}

// ---------------- W_X [512,2048,3,3] f32 -> WT [9,512,2048] f16 ------------
__global__ __launch_bounds__(256) void ocr_cvt_w(const float* __restrict__ Wx,
                                                 unsigned short* __restrict__ WT) {
  int oc = blockIdx.x >> 3;
  int ic = (blockIdx.x & 7) * 256 + threadIdx.x;
  const float* wp = Wx + ((size_t)oc * 2048 + ic) * 9;
  float v[9];
  #pragma unroll
  for (int t = 0; t < 9; ++t) v[t] = wp[t];
  #pragma unroll
  for (int t = 0; t < 9; ++t)
    WT[((size_t)t * 512 + oc) * 2048 + ic] = f2h(v[t]);
}

// ---------------- fused f32 -> f16 for W_psi (131072) + W_g (524288) -------
__global__ __launch_bounds__(256) void ocr_cvt_h2(const float* __restrict__ inA,
                                                  unsigned short* __restrict__ outA,
                                                  const float* __restrict__ inB,
                                                  unsigned short* __restrict__ outB) {
  int i = blockIdx.x * 256 + threadIdx.x;
  if (i < 131072) outA[i] = f2h(inA[i]);
  if (i < 524288) outB[i] = f2h(inB[i]);
}

// ---------------- conv 3x3 2048->512, f16 MFMA, 16 waves (r9 structure) ----
// 1024 threads / 16 waves: ws=wv&7 owns h-row h0+ws (64oc x 64px, acc 4x4);
// kh=wv>>3 owns a tap half (tap4 split by nw pairs -> 72 MFMA/wave balanced).
// 4 waves/SIMD so LDS reads of some waves overlap others' MFMA.
// LDS: dbuf 2 x (A 38912B [tap9][kg4][66] + B 43008B [row10][kg4][66]) =160KiB.
// Staging: 80 chunks = exactly 5/wave; single-syncthreads dbuf loop
// (loads issued at top, drain hidden under compute).
__global__ __launch_bounds__(1024, 4) void ocr_conv_mfma(const unsigned short* __restrict__ xT,
                                                         const unsigned short* __restrict__ WT,
                                                         float* __restrict__ Xf) {
  __shared__ __align__(16) char lds_raw[163840];
  float* red = (float*)lds_raw;

  const int t = threadIdx.x;
  const int wv = t >> 6, lane = t & 63;
  const int kg = lane >> 4, lc = lane & 15;
  const int ws = wv & 7, kh = wv >> 3;

  const int hg  = blockIdx.x & 7;
  const int b   = (blockIdx.x >> 3) & 3;
  const int oct = blockIdx.x >> 5;
  const int oc0 = oct * 64, h0 = hg * 8;

  // 5 staging chunks per wave (80 total: 0-37 A, 38-79 B), full-wave,
  // wave-uniform LDS base, clamped (dup) loads for pad/tail cells (never read).
  const char* gp[5]; int lo[5];
  #pragma unroll
  for (int i = 0; i < 5; ++i) {
    int c = wv * 5 + i;
    lo[i] = c * 1024;
    if (c < 38) {
      int cell = c * 64 + lane; if (cell > 2375) cell = 2375;
      int r = cell / 66, col = cell - r * 66; if (col > 63) col = 63;
      int tap = r >> 2, kgs = r & 3;
      gp[i] = (const char*)WT + (size_t)(((tap * 512 + oc0 + col) * 2048) + kgs * 8) * 2;
    } else {
      int c2 = c - 38;
      int cell = c2 * 64 + lane; if (cell > 2639) cell = 2639;
      int r = cell / 66, col = cell - r * 66;
      int row = r >> 2, kgs = r & 3;
      gp[i] = (const char*)xT + (size_t)((((b * 66 + h0 + row) * 66 + col) * 2048) + kgs * 8) * 2;
    }
  }

  f32x4 acc[4][4] = {};

  // prologue: stage step 0 into buffer 0
  #pragma unroll
  for (int i = 0; i < 5; ++i) gload16(gp[i], lds_raw + lo[i]);
  __syncthreads();

  int cur = 0;
  #pragma unroll 1
  for (int step = 0; step < 64; ++step) {
    if (step < 63) {                      // issue next-step loads FIRST
      unsigned adv = (unsigned)(step + 1) * 64u;   // 32 ic = 64B per step
      int nxt = (cur ^ 1) * 81920;
      #pragma unroll
      for (int i = 0; i < 5; ++i) gload16(gp[i] + adv, lds_raw + nxt + lo[i]);
    }
    const short* As = (const short*)(lds_raw + cur * 81920);
    const short* Bs = (const short*)(lds_raw + cur * 81920 + 38912);
    #pragma unroll
    for (int j = 0; j < 5; ++j) {
      const int tap = kh * 4 + j;         // kh0: 0..4, kh1: 4..8
      const int dh = tap / 3, dw = tap - dh * 3;
      f16x8 av[4];
      #pragma unroll
      for (int mi = 0; mi < 4; ++mi)
        av[mi] = *(const f16x8*)&As[((tap * 4 + kg) * 66 + mi * 16 + lc) * 8];
      const int row = ws + dh;
      // tap 4 split: kh0 does nw{0,1}, kh1 does nw{2,3}
      const int nw0 = (tap == 4) ? (kh ? 2 : 0) : 0;
      const int nwN = (tap == 4) ? (nw0 + 2) : 4;
      #pragma unroll
      for (int nw = 0; nw < 4; ++nw) {
        if (nw >= nw0 && nw < nwN) {
          f16x8 bv = *(const f16x8*)&Bs[((row * 4 + kg) * 66 + nw * 16 + lc + dw) * 8];
          #pragma unroll
          for (int mi = 0; mi < 4; ++mi)
            acc[mi][nw] = __builtin_amdgcn_mfma_f32_16x16x32_f16(av[mi], bv, acc[mi][nw], 0, 0, 0);
        }
      }
    }
    __syncthreads();   // drains staged loads (issued pre-compute: hidden)
    cur ^= 1;
  }

  // split-tap reduction through LDS (128KB, reuses dbuf region), then write
  if (kh == 1) {
    #pragma unroll
    for (int mi = 0; mi < 4; ++mi)
      #pragma unroll
      for (int nw = 0; nw < 4; ++nw)
        *(f32x4*)&red[(((ws * 16 + mi * 4 + nw) * 64) + lane) * 4] = acc[mi][nw];
  }
  __syncthreads();
  if (kh == 0) {
    const int h = h0 + ws;
    #pragma unroll
    for (int mi = 0; mi < 4; ++mi) {
      #pragma unroll
      for (int nw = 0; nw < 4; ++nw) {
        f32x4 other = *(const f32x4*)&red[(((ws * 16 + mi * 4 + nw) * 64) + lane) * 4];
        f32x4 s = acc[mi][nw] + other;
        #pragma unroll
        for (int r = 0; r < 4; ++r) {
          int oc = oc0 + mi * 16 + (lane >> 4) * 4 + r;
          int w = nw * 16 + lc;
          Xf[(((size_t)b * 512 + oc) * 64 + h) * 64 + w] = s[r];
        }
      }
    }
  }
}

// ------ f16 MFMA GEMM (counted-vmcnt dbuf): C[b,O,4096]=A[O,K]@B[b,4096,LDB]
template<int K, int OT, int NT, int NWM, int NWN, int LDB>
__global__ __launch_bounds__(256) void ocr_gemm_h(const unsigned short* __restrict__ Ah,
                                                  const unsigned short* __restrict__ Bh,
                                                  float* __restrict__ Cm, int O) {
  static_assert(NT == 128, "NT fixed");
  constexpr int MI = OT / NWM / 16;
  constexpr int NI = NT / NWN / 16;
  constexpr int SA = OT + 2, SB = NT + 2;
  constexpr int ACELL = 4 * OT / 256;
  constexpr int ABUF = 4 * SA * 8;   // shorts per buffer
  constexpr int BBUF = 4 * SB * 8;
  constexpr int NS = K / 32;
  constexpr int LPW = ACELL + 2;     // loads per wave per step
  __shared__ __align__(16) short As_s[2 * ABUF];
  __shared__ __align__(16) short Bs_s[2 * BBUF];

  const int t = threadIdx.x;
  const int wv = t >> 6, lane = t & 63;
  const int kg = lane >> 4, lc = lane & 15;
  const int wm = wv / NWN, wn = wv % NWN;

  const int n0 = blockIdx.x * NT, o0 = blockIdx.y * OT, b = blockIdx.z;

  const char* aBase[ACELL]; int aLds[ACELL];
  #pragma unroll
  for (int r = 0; r < ACELL; ++r) {
    int flat0 = r * 256 + (t & 448);               // wave base
    int flat  = flat0 + lane;
    int kgs = flat / OT, ol = flat % OT;
    aBase[r] = (const char*)(Ah + ((size_t)(o0 + ol)) * K + kgs * 8);
    aLds[r] = ((flat0 / OT) * SA + (flat0 % OT)) * 16;  // bytes, wave-uniform
  }
  const char* bBase[2]; int bLds[2];
  #pragma unroll
  for (int r = 0; r < 2; ++r) {
    int flat0 = r * 256 + (t & 448);
    int flat  = flat0 + lane;
    int kgs = flat >> 7, nl = flat & 127;
    bBase[r] = (const char*)(Bh + ((size_t)b * 4096 + n0 + nl) * LDB + kgs * 8);
    bLds[r] = ((flat0 >> 7) * SB + (flat0 & 127)) * 16;
  }

  f32x4 acc[MI][NI] = {};
  #pragma unroll
  for (int r = 0; r < ACELL; ++r) gload16(aBase[r], (char*)As_s + aLds[r]);
  #pragma unroll
  for (int r = 0; r < 2; ++r) gload16(bBase[r], (char*)Bs_s + bLds[r]);
  asm volatile("s_waitcnt vmcnt(0)" ::: "memory");
  __builtin_amdgcn_s_barrier();

  int cur = 0;
  #pragma unroll 1
  for (int step = 0; step < NS; ++step) {
    if (step + 1 < NS) {
      unsigned adv = (unsigned)(step + 1) * 64u;
      int nA = (cur ^ 1) * ABUF * 2, nB = (cur ^ 1) * BBUF * 2;  // bytes
      #pragma unroll
      for (int r = 0; r < ACELL; ++r) gload16(aBase[r] + adv, (char*)As_s + nA + aLds[r]);
      #pragma unroll
      for (int r = 0; r < 2; ++r) gload16(bBase[r] + adv, (char*)Bs_s + nB + bLds[r]);
      if constexpr (LPW == 3) asm volatile("s_waitcnt vmcnt(3)" ::: "memory");
      else                    asm volatile("s_waitcnt vmcnt(4)" ::: "memory");
    } else {
      asm volatile("s_waitcnt vmcnt(0)" ::: "memory");
    }
    __builtin_amdgcn_s_barrier();

    const short* As = As_s + cur * ABUF;
    const short* Bsc = Bs_s + cur * BBUF;
    f16x8 av[MI], bv[NI];
    #pragma unroll
    for (int mi = 0; mi < MI; ++mi)
      av[mi] = *(const f16x8*)&As[(kg * SA + wm * (MI * 16) + mi * 16 + lc) * 8];
    #pragma unroll
    for (int ni = 0; ni < NI; ++ni)
      bv[ni] = *(const f16x8*)&Bsc[(kg * SB + wn * (NI * 16) + ni * 16 + lc) * 8];
    __builtin_amdgcn_s_setprio(1);
    #pragma unroll
    for (int mi = 0; mi < MI; ++mi)
      #pragma unroll
      for (int ni = 0; ni < NI; ++ni)
        acc[mi][ni] = __builtin_amdgcn_mfma_f32_16x16x32_f16(av[mi], bv[ni], acc[mi][ni], 0, 0, 0);
    __builtin_amdgcn_s_setprio(0);
    asm volatile("s_waitcnt lgkmcnt(0)" ::: "memory");
    __builtin_amdgcn_sched_barrier(0);
    __builtin_amdgcn_s_barrier();
    cur ^= 1;
  }
  #pragma unroll
  for (int mi = 0; mi < MI; ++mi) {
    #pragma unroll
    for (int ni = 0; ni < NI; ++ni) {
      int n = n0 + wn * (NI * 16) + ni * 16 + lc;
      #pragma unroll
      for (int r = 0; r < 4; ++r) {
        int oc = o0 + wm * (MI * 16) + mi * 16 + (lane >> 4) * 4 + r;
        Cm[((size_t)b * O + oc) * 4096 + n] = acc[mi][ni][r];
      }
    }
  }
}

// ------- transpose-convert + fused BN/relu: f32 [b,C,4096] -> f16 ----------
__global__ __launch_bounds__(256) void ocr_t2h(const float* __restrict__ in,
                                               const float* __restrict__ scale,
                                               const float* __restrict__ shift,
                                               unsigned short* __restrict__ out,
                                               int C, int coff) {
  __shared__ float tile[64][65];
  int n0 = blockIdx.x * 64, c0 = blockIdx.y * 64, b = blockIdx.z;
  int t = threadIdx.x;
  #pragma unroll
  for (int r = 0; r < 16; ++r) {
    int c_l = r * 4 + (t >> 6), n_l = t & 63;
    tile[c_l][n_l] = in[((size_t)(b * C + c0 + c_l)) * 4096 + n0 + n_l];
  }
  __syncthreads();
  int n_l = t >> 2, cb = (t & 3) * 16;
  ushortx8 o0v, o1v;
  #pragma unroll
  for (int j = 0; j < 8; ++j) {
    int c = c0 + cb + j;
    o0v[j] = f2h(fmaxf(0.f, tile[cb + j][n_l] * scale[c] + shift[c]));
  }
  #pragma unroll
  for (int j = 0; j < 8; ++j) {
    int c = c0 + cb + 8 + j;
    o1v[j] = f2h(fmaxf(0.f, tile[cb + 8 + j][n_l] * scale[c] + shift[c]));
  }
  size_t base = ((size_t)b * 4096 + n0 + n_l) * 1024 + coff + c0 + cb;
  *(ushortx8*)&out[base] = o0v;
  *(ushortx8*)&out[base + 8] = o1v;
}

// ---------------- per-channel stats over [4][C][4096] -> scale/shift -------
__global__ __launch_bounds__(256) void ocr_chan_stats(const float* __restrict__ buf,
                                                      const float* __restrict__ gamma,
                                                      const float* __restrict__ beta,
                                                      float* __restrict__ scale,
                                                      float* __restrict__ shift, int C) {
  int c = blockIdx.x, t = threadIdx.x;
  float s = 0.f, q = 0.f;
  for (int b = 0; b < 4; ++b) {
    const float* p = buf + ((size_t)b * C + c) * 4096;
    for (int i = t; i < 4096; i += 256) { float v = p[i]; s += v; q += v * v; }
  }
  __shared__ float ls[256], lq[256];
  ls[t] = s; lq[t] = q; __syncthreads();
  for (int off = 128; off > 0; off >>= 1) {
    if (t < off) { ls[t] += ls[t + off]; lq[t] += lq[t + off]; }
    __syncthreads();
  }
  if (t == 0) {
    float mean = ls[0] / 16384.f;
    float var  = lq[0] / 16384.f - mean * mean;
    float sc   = gamma[c] * rsqrtf(var + EPSV);
    scale[c] = sc; shift[c] = beta[c] - mean * sc;
  }
}

// ---------------- L = W_L @ llf + b_L  (4-deep MLP on c) -------------------
__global__ __launch_bounds__(256) void ocr_lproj(const float* __restrict__ llf,
                                                 const float* __restrict__ WL,
                                                 const float* __restrict__ bL,
                                                 float* __restrict__ L) {
  int h = blockIdx.x, b = blockIdx.y;
  int t = threadIdx.x, w = t & 63, csub = t >> 6;
  float acc[19];
  #pragma unroll
  for (int k = 0; k < 19; ++k) acc[k] = 0.f;
  const float* base = llf + ((size_t)b * 1024 + csub * 256) * 4096 + h * 64 + w;
  #pragma unroll 1
  for (int c4 = 0; c4 < 64; ++c4) {
    float lv[4];
    #pragma unroll
    for (int i = 0; i < 4; ++i) lv[i] = base[(size_t)(c4 + i * 64) * 4096];
    #pragma unroll
    for (int i = 0; i < 4; ++i) {
      const float* wl = &WL[csub * 256 + c4 + i * 64];
      #pragma unroll
      for (int k = 0; k < 19; ++k) acc[k] += wl[k * 1024] * lv[i];
    }
  }
  __shared__ float red[4][64][19];
  #pragma unroll
  for (int k = 0; k < 19; ++k) red[csub][w][k] = acc[k];
  __syncthreads();
  if (csub == 0) {
    #pragma unroll
    for (int k = 0; k < 19; ++k) {
      float s = red[0][w][k] + red[1][w][k] + red[2][w][k] + red[3][w][k] + bL[k];
      L[((size_t)b * 19 + k) * 4096 + h * 64 + w] = s;
    }
  }
}

// ---------------- in-place softmax over last dim (4096) --------------------
__global__ __launch_bounds__(256) void ocr_softmax4096(float* __restrict__ buf) {
  int row = blockIdx.x, t = threadIdx.x;
  float* p = buf + (size_t)row * 4096;
  __shared__ float ls[256];
  float m = -1e30f;
  for (int i = t; i < 4096; i += 256) m = fmaxf(m, p[i]);
  ls[t] = m; __syncthreads();
  for (int off = 128; off > 0; off >>= 1) { if (t < off) ls[t] = fmaxf(ls[t], ls[t + off]); __syncthreads(); }
  m = ls[0]; __syncthreads();
  float s = 0.f;
  for (int i = t; i < 4096; i += 256) { float e = __expf(p[i] - m); p[i] = e; s += e; }
  ls[t] = s; __syncthreads();
  for (int off = 128; off > 0; off >>= 1) { if (t < off) ls[t] += ls[t + off]; __syncthreads(); }
  float inv = 1.f / ls[0];
  for (int i = t; i < 4096; i += 256) p[i] *= inv;
}

// -------- f_k[b,c,k] = sum_n M[b,k,n] * relu(Xf*sc+sh)[b,c,n] (fused BN) ---
__global__ __launch_bounds__(256) void ocr_fk(const float* __restrict__ M,
                                              const float* __restrict__ Xf,
                                              const float* __restrict__ scale,
                                              const float* __restrict__ shift,
                                              float* __restrict__ fk) {
  int c = blockIdx.x, b = blockIdx.y, t = threadIdx.x;
  float acc[19];
  #pragma unroll
  for (int k = 0; k < 19; ++k) acc[k] = 0.f;
  const float* xp = Xf + ((size_t)b * 512 + c) * 4096;
  const float* mp = M + (size_t)b * 19 * 4096;
  float sc = scale[c], sh = shift[c];
  for (int n = t; n < 4096; n += 256) {
    float xv = fmaxf(0.f, xp[n] * sc + sh);
    #pragma unroll
    for (int k = 0; k < 19; ++k) acc[k] += mp[k * 4096 + n] * xv;
  }
  __shared__ float red[19 * 256];
  #pragma unroll
  for (int k = 0; k < 19; ++k) red[k * 256 + t] = acc[k];
  __syncthreads();
  for (int off = 128; off > 0; off >>= 1) {
    if (t < off) {
      #pragma unroll
      for (int k = 0; k < 19; ++k) red[k * 256 + t] += red[k * 256 + t + off];
    }
    __syncthreads();
  }
  if (t < 19) fk[((size_t)b * 512 + c) * 19 + t] = red[t * 256];
}

// ---------------- q/d fused: qry + dlt in one launch -----------------------
__global__ __launch_bounds__(256) void ocr_qd2(const float* __restrict__ Wphi,
                                               const float* __restrict__ Wdelta,
                                               const float* __restrict__ fk,
                                               float* __restrict__ qry,
                                               float* __restrict__ dlt) {
  int blk = blockIdx.x;
  const float* Wm = (blk < 76) ? Wphi : Wdelta;
  float* out = (blk < 76) ? qry : dlt;
  int tid = (blk < 76 ? blk : blk - 76) * 256 + threadIdx.x;
  if (tid >= 4 * 256 * 19) return;
  int k = tid % 19, o = (tid / 19) % 256, b = tid / (19 * 256);
  const float* fp = fk + (size_t)b * 512 * 19 + k;
  const float* wp = Wm + (size_t)o * 512;
  float acc = 0.f;
  for (int c = 0; c < 512; ++c) acc += wp[c] * fp[c * 19];
  out[tid] = acc;
}

// ---------------- BN76 fused: qry (blocks 0-255) + dlt (256-511) -----------
__global__ __launch_bounds__(128) void ocr_bn76x2(float* __restrict__ qry,
                                                  float* __restrict__ dlt,
                                                  const float* __restrict__ g_phi,
                                                  const float* __restrict__ be_phi,
                                                  const float* __restrict__ g_delta,
                                                  const float* __restrict__ be_delta) {
  bool second = blockIdx.x >= 256;
  int o = blockIdx.x & 255, t = threadIdx.x;
  float* buf = second ? dlt : qry;
  const float* gamma = second ? g_delta : g_phi;
  const float* beta  = second ? be_delta : be_phi;
  bool act = t < 76;
  float v = 0.f;
  size_t idx = 0;
  if (act) {
    int b = t / 19, k = t % 19;
    idx = ((size_t)b * 256 + o) * 19 + k;
    v = buf[idx];
  }
  __shared__ float ls[128], lq[128];
  ls[t] = act ? v : 0.f; lq[t] = act ? v * v : 0.f; __syncthreads();
  for (int off = 64; off > 0; off >>= 1) { if (t < off) { ls[t] += ls[t + off]; lq[t] += lq[t + off]; } __syncthreads(); }
  __shared__ float s_sc, s_sh;
  if (t == 0) {
    float mean = ls[0] / 76.f;
    float var  = lq[0] / 76.f - mean * mean;
    float sc   = gamma[o] * rsqrtf(var + EPSV);
    s_sc = sc; s_sh = beta[o] - mean * sc;
  }
  __syncthreads();
  if (act) buf[idx] = fmaxf(0.f, v * s_sc + s_sh);
}

// ------- logit + softmax over nc(19), key BN fused, 4-deep MLP -------------
__global__ __launch_bounds__(256) void ocr_attn(const float* __restrict__ query,
                                                const float* __restrict__ key,
                                                const float* __restrict__ scale,
                                                const float* __restrict__ shift,
                                                float* __restrict__ attn) {
  int n0 = blockIdx.x * 64, b = blockIdx.y;
  int t = threadIdx.x, nl = t & 63, qsub = t >> 6;
  __shared__ float ql[256 * 19];
  for (int i = t; i < 256 * 19; i += 256) ql[i] = query[(size_t)b * 256 * 19 + i];
  __syncthreads();
  float acc[19];
  #pragma unroll
  for (int k = 0; k < 19; ++k) acc[k] = 0.f;
  const float* kp = key + ((size_t)b * 256 + qsub * 64) * 4096 + n0 + nl;
  #pragma unroll 1
  for (int q4 = 0; q4 < 64; q4 += 4) {
    float kv[4];
    #pragma unroll
    for (int i = 0; i < 4; ++i) kv[i] = kp[(size_t)(q4 + i) * 4096];
    #pragma unroll
    for (int i = 0; i < 4; ++i) {
      int ch = qsub * 64 + q4 + i;
      float kva = fmaxf(0.f, kv[i] * scale[ch] + shift[ch]);
      const float* qq = &ql[ch * 19];
      #pragma unroll
      for (int k = 0; k < 19; ++k) acc[k] += qq[k] * kva;
    }
  }
  __shared__ float red[4][64][19];
  #pragma unroll
  for (int k = 0; k < 19; ++k) red[qsub][nl][k] = acc[k];
  __syncthreads();
  if (qsub == 0) {
    float v[19]; float m = -1e30f;
    #pragma unroll
    for (int k = 0; k < 19; ++k) {
      v[k] = red[0][nl][k] + red[1][nl][k] + red[2][nl][k] + red[3][nl][k];
      m = fmaxf(m, v[k]);
    }
    float s = 0.f;
    #pragma unroll
    for (int k = 0; k < 19; ++k) { v[k] = __expf(v[k] - m); s += v[k]; }
    float inv = 1.f / s;
    #pragma unroll
    for (int k = 0; k < 19; ++k)
      attn[((size_t)b * 19 + k) * 4096 + n0 + nl] = v[k] * inv;
  }
}

// ---------------- Wd[b,o,k] = sum_q W_rho[o,q] * dlt[b,q,k] ----------------
__global__ __launch_bounds__(256) void ocr_wd(const float* __restrict__ Wrho,
                                              const float* __restrict__ dlt,
                                              float* __restrict__ Wd) {
  int tid = blockIdx.x * 256 + threadIdx.x;
  if (tid >= 4 * 512 * 19) return;
  int k = tid % 19, o = (tid / 19) % 512, b = tid / (19 * 512);
  const float* dp = dlt + (size_t)b * 256 * 19 + k;
  const float* wp = Wrho + (size_t)o * 256;
  float acc = 0.f;
  for (int q = 0; q < 256; ++q) acc += wp[q] * dp[q * 19];
  Wd[tid] = acc;
}

// ------- Gram partials: G[b] += attn_chunk @ attn_chunk^T, RS[b] += rowsum -
__global__ __launch_bounds__(384) void ocr_gram(const float* __restrict__ attn,
                                                float* __restrict__ G,
                                                float* __restrict__ RS) {
  __shared__ float al[19][513];
  int n0 = blockIdx.x * 512, b = blockIdx.y, t = threadIdx.x;
  for (int i = t; i < 19 * 512; i += 384) {
    int k = i >> 9, n = i & 511;
    al[k][n] = attn[((size_t)b * 19 + k) * 4096 + n0 + n];
  }
  __syncthreads();
  if (t < 361) {
    int k1 = t / 19, k2 = t % 19;
    float s = 0.f;
    for (int n = 0; n < 512; ++n) s += al[k1][n] * al[k2][n];
    atomicAdd(&G[(b * 19 + k1) * 19 + k2], s);
  } else if (t < 380) {
    int k = t - 361;
    float s = 0.f;
    for (int n = 0; n < 512; ++n) s += al[k][n];
    atomicAdd(&RS[b * 19 + k], s);
  }
}

// ------- Xobj scale/shift from Gram: one block of 512 (one thread per o) ---
__global__ __launch_bounds__(512) void ocr_xobj_fin(const float* __restrict__ Wd,
                                                    const float* __restrict__ G,
                                                    const float* __restrict__ RS,
                                                    const float* __restrict__ gamma,
                                                    const float* __restrict__ beta,
                                                    float* __restrict__ scale,
                                                    float* __restrict__ shift) {
  int o = threadIdx.x;
  float s = 0.f, q = 0.f;
  for (int b = 0; b < 4; ++b) {
    float wd[19];
    #pragma unroll
    for (int k = 0; k < 19; ++k) wd[k] = Wd[((size_t)b * 512 + o) * 19 + k];
    const float* g = &G[b * 361];
    const float* rs = &RS[b * 19];
    #pragma unroll
    for (int k = 0; k < 19; ++k) s += wd[k] * rs[k];
    for (int k1 = 0; k1 < 19; ++k1) {
      float tacc = 0.f;
      #pragma unroll
      for (int k2 = 0; k2 < 19; ++k2) tacc += g[k1 * 19 + k2] * wd[k2];
      q += wd[k1] * tacc;
    }
  }
  float mean = s / 16384.f;
  float var  = q / 16384.f - mean * mean;
  float sc   = gamma[o] * rsqrtf(var + EPSV);
  scale[o] = sc; shift[o] = beta[o] - mean * sc;
}

// ---------------- Xobj apply: relu(scale*(Wd@attn)+shift) -> concat f16 ----
__global__ __launch_bounds__(512) void ocr_xobj_apply(const float* __restrict__ Wd,
                                                      const float* __restrict__ attn,
                                                      const float* __restrict__ scale,
                                                      const float* __restrict__ shift,
                                                      unsigned short* __restrict__ ch) {
  __shared__ float al[19][256];
  int n0 = blockIdx.x * 256, b = blockIdx.y, o = threadIdx.x;
  for (int idx = o; idx < 19 * 256; idx += 512) {
    int k = idx >> 8, nl = idx & 255;
    al[k][nl] = attn[((size_t)b * 19 + k) * 4096 + n0 + nl];
  }
  float wd[19];
  #pragma unroll
  for (int k = 0; k < 19; ++k) wd[k] = Wd[((size_t)b * 512 + o) * 19 + k];
  float sc = scale[o], sh = shift[o];
  __syncthreads();
  #pragma unroll 1
  for (int nl = 0; nl < 256; ++nl) {
    float v = 0.f;
    #pragma unroll
    for (int k = 0; k < 19; ++k) v += wd[k] * al[k][nl];
    v = fmaxf(0.f, v * sc + sh);
    ch[((size_t)b * 4096 + n0 + nl) * 1024 + 512 + o] = f2h(v);
  }
}

// ---- out[b,19,n] = W_out @ relu(Xbar*sc+sh) + b_out (BN fused, 4-MLP) -----
__global__ __launch_bounds__(256) void ocr_out(const float* __restrict__ Wout,
                                               const float* __restrict__ bout,
                                               const float* __restrict__ Xbar,
                                               const float* __restrict__ scale,
                                               const float* __restrict__ shift,
                                               float* __restrict__ out) {
  int n0 = blockIdx.x * 64, b = blockIdx.y;
  int t = threadIdx.x, nl = t & 63, csub = t >> 6;
  float acc[19];
  #pragma unroll
  for (int k = 0; k < 19; ++k) acc[k] = 0.f;
  const float* base = Xbar + ((size_t)b * 512 + csub * 128) * 4096 + n0 + nl;
  #pragma unroll 1
  for (int c4 = 0; c4 < 128; c4 += 4) {
    float xv[4];
    #pragma unroll
    for (int i = 0; i < 4; ++i) xv[i] = base[(size_t)(c4 + i) * 4096];
    #pragma unroll
    for (int i = 0; i < 4; ++i) {
      int chn = csub * 128 + c4 + i;
      float a = fmaxf(0.f, xv[i] * scale[chn] + shift[chn]);
      #pragma unroll
      for (int k = 0; k < 19; ++k) acc[k] += Wout[k * 512 + chn] * a;
    }
  }
  __shared__ float red[4][64][19];
  #pragma unroll
  for (int k = 0; k < 19; ++k) red[csub][nl][k] = acc[k];
  __syncthreads();
  if (csub == 0) {
    #pragma unroll
    for (int k = 0; k < 19; ++k) {
      float s = red[0][nl][k] + red[1][nl][k] + red[2][nl][k] + red[3][nl][k] + bout[k];
      out[((size_t)b * 19 + k) * 4096 + n0 + nl] = s;
    }
  }
}

// ---------------------------------------------------------------------------
extern "C" void kernel_launch(void* const* d_in, const int* in_sizes, int n_in,
                              void* d_out, int out_size, void* d_ws, size_t ws_size,
                              hipStream_t stream) {
  const float* x    = (const float*)d_in[0];
  const float* llf  = (const float*)d_in[1];
  const float* W_L  = (const float*)d_in[2];
  const float* b_L  = (const float*)d_in[3];
  const float* W_X  = (const float*)d_in[4];
  const float* g_X  = (const float*)d_in[5];
  const float* be_X = (const float*)d_in[6];
  const float* W_phi = (const float*)d_in[7];
  const float* g_phi = (const float*)d_in[8];
  const float* be_phi = (const float*)d_in[9];
  const float* W_psi = (const float*)d_in[10];
  const float* g_psi = (const float*)d_in[11];
  const float* be_psi = (const float*)d_in[12];
  const float* W_delta = (const float*)d_in[13];
  const float* g_delta = (const float*)d_in[14];
  const float* be_delta = (const float*)d_in[15];
  const float* W_rho = (const float*)d_in[16];
  const float* g_rho = (const float*)d_in[17];
  const float* be_rho = (const float*)d_in[18];
  const float* W_g  = (const float*)d_in[19];
  const float* g_g  = (const float*)d_in[20];
  const float* be_g = (const float*)d_in[21];
  const float* W_out = (const float*)d_in[22];
  const float* b_out = (const float*)d_in[23];

  float* ws = (float*)d_ws;
  float* Xf = ws;                                        // 8388608 fl, persistent (raw conv out)
  float* U  = ws + 8388608;
  // conv-stage aliases (dead after conv):
  unsigned short* xT = (unsigned short*)U;               // 35684352 u16 = 17842176 fl
  unsigned short* WT = (unsigned short*)(U + 17842176);  // 9437184 u16 (ends 22560768 fl)
  // post-conv buffers (overlap xT/WT region):
  unsigned short* concat_h = (unsigned short*)U;         // [b][4096][1024] f16 = 8388608 fl
  float* key  = U + 8388608;                             // 4194304 fl (raw)
  float* Xbar = U + 12582912;                            // 8388608 fl (raw, ends 20971520)
  // small region beyond WT end (never overlaps conv data):
  float* SM   = U + 22560768;
  float* M     = SM;                                     // 311296
  float* attnb = SM + 311296;                            // 311296
  float* fk    = SM + 622592;                            // 38912
  float* qry   = SM + 661504;                            // 19456
  float* dlt   = SM + 680960;                            // 19456
  float* Wd    = SM + 700416;                            // 38912
  float* st    = SM + 739328;                            // 4096
  unsigned short* Wpsi_h = (unsigned short*)(SM + 743424);  // 131072 u16
  unsigned short* Wg_h   = (unsigned short*)(SM + 808960);  // 524288 u16
  float* Gm    = SM + 1071104;                           // 4*361 = 1444
  float* RSm   = SM + 1072548;                           // 4*19  = 76
  float* scX = st,        *shX = st + 512;
  float* scP = st + 1024, *shP = st + 1280;
  float* scR = st + 1536, *shR = st + 2048;
  float* scG = st + 2560, *shG = st + 3072;

  // 0. prep: halo-zero (border cells only) + f16 conversions
  ocr_halo_zero<<<dim3(4, 4), 256, 0, stream>>>(xT);
  ocr_cvt_x<<<dim3(32, 64, 4), 256, 0, stream>>>(x, xT);
  ocr_cvt_w<<<dim3(4096), 256, 0, stream>>>(W_X, WT);
  ocr_cvt_h2<<<dim3(2048), 256, 0, stream>>>(W_psi, Wpsi_h, W_g, Wg_h);
  hipMemsetAsync(Gm, 0, 1520 * sizeof(float), stream);

  // 1. conv (f16 MFMA, 16 waves, single-barrier dbuf, XCD-swizzled) -> Xf raw
  ocr_conv_mfma<<<dim3(256), 1024, 0, stream>>>(xT, WT, Xf);

  // 2. BN(X) stats only; apply is fused into t2h and fk
  ocr_chan_stats<<<dim3(512), 256, 0, stream>>>(Xf, g_X, be_X, scX, shX, 512);
  // 3. Xf -> concat_h cols [0,512) f16 transposed (BN+relu fused)
  ocr_t2h<<<dim3(64, 8, 4), 256, 0, stream>>>(Xf, scX, shX, concat_h, 512, 0);
  // 4. region head: L -> softmax -> f_k (BN fused) -> query/delta + BN76
  ocr_lproj<<<dim3(64, 4), 256, 0, stream>>>(llf, W_L, b_L, M);
  ocr_softmax4096<<<dim3(76), 256, 0, stream>>>(M);
  ocr_fk<<<dim3(512, 4), 256, 0, stream>>>(M, Xf, scX, shX, fk);
  ocr_qd2<<<dim3(152), 256, 0, stream>>>(W_phi, W_delta, fk, qry, dlt);
  ocr_bn76x2<<<dim3(512), 128, 0, stream>>>(qry, dlt, g_phi, be_phi, g_delta, be_delta);
  // 5. key_raw = W_psi @ concat (f16 MFMA); BN stats; apply fused into attn
  ocr_gemm_h<512, 64, 128, 2, 2, 1024><<<dim3(32, 4, 4), 256, 0, stream>>>(Wpsi_h, concat_h, key, 256);
  ocr_chan_stats<<<dim3(256), 256, 0, stream>>>(key, g_psi, be_psi, scP, shP, 256);
  // 6. attention softmax over nc (key BN+relu fused)
  ocr_attn<<<dim3(64, 4), 256, 0, stream>>>(qry, key, scP, shP, attnb);
  // 7. X_obj = BN(relu(W_rho @ delta @ attn)); stats via Gram algebra (K=19)
  ocr_wd<<<dim3(152), 256, 0, stream>>>(W_rho, dlt, Wd);
  ocr_gram<<<dim3(8, 4), 384, 0, stream>>>(attnb, Gm, RSm);
  ocr_xobj_fin<<<dim3(1), 512, 0, stream>>>(Wd, Gm, RSm, g_rho, be_rho, scR, shR);
  ocr_xobj_apply<<<dim3(16, 4), 512, 0, stream>>>(Wd, attnb, scR, shR, concat_h);
  // 8. Xbar_raw = W_g @ concat (f16 MFMA, K=1024); BN stats; apply fused in out
  ocr_gemm_h<1024, 128, 128, 2, 2, 1024><<<dim3(32, 4, 4), 256, 0, stream>>>(Wg_h, concat_h, Xbar, 512);
  ocr_chan_stats<<<dim3(512), 256, 0, stream>>>(Xbar, g_g, be_g, scG, shG, 512);
  // 9. output projection (Xbar BN+relu fused, 4-deep MLP)
  ocr_out<<<dim3(64, 4), 256, 0, stream>>>(W_out, b_out, Xbar, scG, shG, (float*)d_out);
}